// Round 11
// baseline (116.669 us; speedup 1.0000x reference)
//
#include <hip/hip_runtime.h>
#include <hip/hip_bf16.h>
#include <stdint.h>

#define SS 4096
#define DD 256
#define HH 4
#define KK 64
#define ALPHA 0.18033688011112042f  // 0.125 * log2(e)

typedef float f32x4 __attribute__((ext_vector_type(4)));
typedef short s16x8 __attribute__((ext_vector_type(8)));
typedef unsigned int u32;

__device__ __forceinline__ unsigned short f2bf(float x) {
  union { float f; unsigned u; } v; v.f = x;
  unsigned r = v.u + 0x7fffu + ((v.u >> 16) & 1u);
  return (unsigned short)(r >> 16);
}

__device__ __forceinline__ u32 cvtpk(float lo, float hi) {
  u32 r;
  asm("v_cvt_pk_bf16_f32 %0, %1, %2" : "=v"(r) : "v"(lo), "v"(hi));
  return r;
}

// hardware 2^x via compiler intrinsic (hazard-safe, single v_exp_f32)
#define fexp2(x) __builtin_amdgcn_exp2f(x)

__device__ __forceinline__ void gl_lds16(const unsigned short* g, unsigned short* l) {
  __builtin_amdgcn_global_load_lds(
      (const __attribute__((address_space(1))) u32*)g,
      (__attribute__((address_space(3))) u32*)l, 16, 0, 0);
}

// ---------------- Kernel 0: weight prep ----------------
__global__ void wprep(const float* __restrict__ Wq, const float* __restrict__ Wk,
                      const float* __restrict__ Wv, const float* __restrict__ Wo,
                      unsigned short* __restrict__ Wt, unsigned short* __restrict__ Wot)
{
  const int blk = blockIdx.x, t = threadIdx.x;
  const int rsub = t >> 4;
  const int c0 = (t & 15) * 16;
  if (blk < 48) {
    const int n = blk * 16 + rsub;               // 0..767
    const float* W = (n < 256) ? Wq : ((n < 512) ? Wk : Wv);
    const int nn = n & 255;
    const float sc = (n < 256) ? ALPHA : 1.0f;
    for (int c = c0; c < c0 + 16; ++c)
      Wt[(size_t)n * 256 + c] = f2bf(sc * W[(size_t)c * 256 + nn]);
  } else {
    const int d = (blk - 48) * 16 + rsub;        // 0..255
    for (int c = c0; c < c0 + 16; ++c)
      Wot[(size_t)d * 256 + c] = f2bf(Wo[(size_t)c * 256 + d]);
  }
}

// ---------------- Kernel 1: fused QKV projection (bf16 MFMA, X staged once) ----------------
// 512 blocks x 256 thr; block = 32 rows, ALL THREE matrices. query+value each
// converted once into 16 KB LDS; wave w = head w, 2x4 frag tile per matrix,
// 192 MFMA/wave. Same chunked output contracts as before.
__global__ __launch_bounds__(256, 2) void qkv_mfma(
    const float* __restrict__ query, const float* __restrict__ value,
    const unsigned short* __restrict__ Wt,
    const float* __restrict__ bq, const float* __restrict__ bk,
    const float* __restrict__ bv,
    unsigned short* __restrict__ qb, unsigned short* __restrict__ kbs,
    unsigned short* __restrict__ vts)
{
  __shared__ __align__(16) unsigned short Xq[32 * 256];   // 16 KB, swizzled
  __shared__ __align__(16) unsigned short Xv[32 * 256];   // 16 KB, swizzled

  const int t = threadIdx.x;
  const int w = t >> 6, l = t & 63, lr = l & 15, grp = l >> 4;
  const long r0 = (long)blockIdx.x * 32;

  // stage: thread t -> row t>>3 (0..31), col-eighth (t&7)*32; swizzle ^(row&7)<<3
  {
    const int row = t >> 3;
    const int c0s = (t & 7) * 32;
    const int sw = (row & 7) << 3;
    const float* qp_ = query + (r0 + row) * 256 + c0s;
    const float* vp_ = value + (r0 + row) * 256 + c0s;
    #pragma unroll
    for (int g = 0; g < 4; ++g) {
      f32x4 q0 = *(const f32x4*)(qp_ + g * 8);
      f32x4 q1 = *(const f32x4*)(qp_ + g * 8 + 4);
      union { u32 wd[4]; s16x8 v; } bb;
      bb.wd[0] = cvtpk(q0[0], q0[1]);
      bb.wd[1] = cvtpk(q0[2], q0[3]);
      bb.wd[2] = cvtpk(q1[0], q1[1]);
      bb.wd[3] = cvtpk(q1[2], q1[3]);
      *(s16x8*)&Xq[(row * 256 + c0s + g * 8) ^ sw] = bb.v;
      f32x4 v0 = *(const f32x4*)(vp_ + g * 8);
      f32x4 v1 = *(const f32x4*)(vp_ + g * 8 + 4);
      bb.wd[0] = cvtpk(v0[0], v0[1]);
      bb.wd[1] = cvtpk(v0[2], v0[3]);
      bb.wd[2] = cvtpk(v1[0], v1[1]);
      bb.wd[3] = cvtpk(v1[2], v1[3]);
      *(s16x8*)&Xv[(row * 256 + c0s + g * 8) ^ sw] = bb.v;
    }
  }
  __syncthreads();

  const int n0 = w * 64;                 // head w
  const int swr = (lr & 7) << 3;

  f32x4 aq[2][4] = {}, ak[2][4] = {}, av[2][4] = {};

  for (int k0 = 0; k0 < 256; k0 += 32) {
    s16x8 xq[2], xv[2];
    #pragma unroll
    for (int mt = 0; mt < 2; ++mt) {
      const int idx = ((mt * 16 + lr) * 256 + k0 + grp * 8) ^ swr;
      xq[mt] = *(const s16x8*)&Xq[idx];
      xv[mt] = *(const s16x8*)&Xv[idx];
    }
    #pragma unroll
    for (int nt = 0; nt < 4; ++nt) {
      const size_t wrow = (size_t)(n0 + nt * 16 + lr) * 256 + k0 + grp * 8;
      s16x8 aQ = *(const s16x8*)(Wt + wrow);
      s16x8 aK = *(const s16x8*)(Wt + (size_t)256 * 256 + wrow);
      s16x8 aV = *(const s16x8*)(Wt + (size_t)512 * 256 + wrow);
      #pragma unroll
      for (int mt = 0; mt < 2; ++mt) {
        aq[mt][nt] = __builtin_amdgcn_mfma_f32_16x16x32_bf16(aQ, xq[mt], aq[mt][nt], 0, 0, 0);
        ak[mt][nt] = __builtin_amdgcn_mfma_f32_16x16x32_bf16(aK, xv[mt], ak[mt][nt], 0, 0, 0);
        av[mt][nt] = __builtin_amdgcn_mfma_f32_16x16x32_bf16(xv[mt], aV, av[mt][nt], 0, 0, 0);
      }
    }
  }

  const int b   = (int)(r0 >> 12);
  const int s0  = (int)(r0 & 4095);
  const int kt  = s0 >> 6;
  const int kvb = s0 & 63;               // 0 or 32
  const int bh  = b * 4 + w;
  const size_t base = (size_t)bh * (SS * KK) + (size_t)kt * 4096;

  // Q store: D[n][s], col = s = s0+mt*16+lr, rows n = n0+nt*16+grp*4+e
  #pragma unroll
  for (int nt = 0; nt < 4; ++nt) {
    const int nk = nt * 16 + grp * 4;
    f32x4 bias = *(const f32x4*)&bq[n0 + nk] * ALPHA;
    #pragma unroll
    for (int mt = 0; mt < 2; ++mt) {
      const int s = s0 + mt * 16 + lr;
      f32x4 o = aq[mt][nt] + bias;
      uint2 pk2; pk2.x = cvtpk(o[0], o[1]); pk2.y = cvtpk(o[2], o[3]);
      *(uint2*)&qb[((size_t)bh * SS + s) * KK + nk] = pk2;
    }
  }
  // K store: chunked, kv = kvb+mt*16+lr, d0 = nt*16+grp*4+e
  #pragma unroll
  for (int nt = 0; nt < 4; ++nt) {
    const int d0 = nt * 16 + grp * 4;
    const int cc = d0 >> 5, grpk = (d0 >> 3) & 3, jlo = d0 & 7;
    f32x4 bias = *(const f32x4*)&bk[n0 + d0];
    #pragma unroll
    for (int mt = 0; mt < 2; ++mt) {
      const int kv = kvb + mt * 16 + lr;
      const int chunk = (((kv >> 4) * 2 + cc) * 4 + grpk) * 16 + (kv & 15);
      f32x4 o = ak[mt][nt] + bias;
      uint2 pk2; pk2.x = cvtpk(o[0], o[1]); pk2.y = cvtpk(o[2], o[3]);
      *(uint2*)&kbs[base + chunk * 8 + jlo] = pk2;
    }
  }
  // V store: D[s][n], col = dk = nt*16+lr, rows kv = kvb+mt*16+grp*4+e
  {
    const int kap = (kvb >> 5) & 1;
    #pragma unroll
    for (int nt = 0; nt < 4; ++nt) {
      const float bvn = bv[n0 + nt * 16 + lr];
      const int cb = (nt * 2 + kap) * 64 + grp * 16 + lr;
      #pragma unroll
      for (int mt = 0; mt < 2; ++mt) {
        f32x4 o = av[mt][nt] + bvn;
        uint2 pk2; pk2.x = cvtpk(o[0], o[1]); pk2.y = cvtpk(o[2], o[3]);
        *(uint2*)&vts[base + (size_t)cb * 8 + mt * 4] = pk2;   // j = mt*4 + e
      }
    }
  }
}

// ---------------- Kernel 2: causal flash attention (triple-buffer, counted vmcnt) ----------------
// 512 blocks x 256 thr (4 waves x 32 q-rows). bh = i&15, pr = (i>>4)&15, role = i>>8.
// 33 tile-steps/block (KV-split exact balance). Prefetch depth 2 (3 LDS bufs):
// per step issue 4 gl_lds, then s_waitcnt vmcnt(8) (2 newest batches stay in
// flight -> L2/L3 latency spans 2 steps) + raw s_barrier. Trailing s_barrier
// protects buffer reuse (distance 3). Fixed-max softmax; l via ones-MFMA.
__global__ __launch_bounds__(256, 2) void attn(
    const unsigned short* __restrict__ qb,
    const unsigned short* __restrict__ kbs,
    const unsigned short* __restrict__ vts,
    float* __restrict__ num0, float* __restrict__ num1,
    float* __restrict__ lb0, float* __restrict__ lb1)
{
  __shared__ __align__(16) unsigned short Kl[3][4096];
  __shared__ __align__(16) unsigned short Vl[3][4096];

  const int t = threadIdx.x;
  const int w = t >> 6, l = t & 63, lr = l & 15, grp = l >> 4;

  const int i    = blockIdx.x;
  const int bh   = i & 15;
  const int pr   = (i >> 4) & 15;
  const int role = i >> 8;
  const int b = bh >> 2, h = bh & 3;
  const int phA_last = 2 * pr + 1;

  const unsigned short* kbase = kbs + (size_t)bh * (SS * KK);
  const unsigned short* vbase = vts + (size_t)bh * (SS * KK);
  const unsigned short* qpb   = qb  + (size_t)bh * (SS * KK);

  int sup = (role == 0) ? pr : (31 - pr);

  s16x8 qf[2][2];
  #pragma unroll
  for (int q2 = 0; q2 < 2; ++q2) {
    const unsigned short* qp = qpb + (size_t)(sup * 128 + w * 32 + q2 * 16 + lr) * KK;
    qf[q2][0] = *(const s16x8*)(qp + grp * 8);
    qf[q2][1] = *(const s16x8*)(qp + 32 + grp * 8);
  }

  s16x8 ones;
  #pragma unroll
  for (int e = 0; e < 8; ++e) ones[e] = (short)0x3F80;   // bf16 1.0
  const f32x4 minit = {-16.f, -16.f, -16.f, -16.f};

  f32x4 cacc[2][4] = {};
  f32x4 lacc[2] = {};

  const int off0 = (w * 64 + l) * 8;
  const int off1 = ((4 + w) * 64 + l) * 8;

  // tile index for logical step s (clamped; tail prefetches are redundant but valid)
  auto ktfor = [&](int s) {
    if (s > 32) s = 32;
    return (role == 0) ? ((s <= phA_last) ? s : (s - (phA_last + 1)))
                       : (31 - 2 * pr + s);
  };
  auto stage = [&](int kt, int bi) {
    const unsigned short* ks = kbase + (size_t)kt * 4096;
    const unsigned short* vs = vbase + (size_t)kt * 4096;
    gl_lds16(ks + off0, &Kl[bi][w * 512]);
    gl_lds16(ks + off1, &Kl[bi][(4 + w) * 512]);
    gl_lds16(vs + off0, &Vl[bi][w * 512]);
    gl_lds16(vs + off1, &Vl[bi][(4 + w) * 512]);
  };

  // prologue: batches for steps 0 and 1
  stage(ktfor(0), 0);
  stage(ktfor(1), 1);

  for (int ss = 0; ss <= 32; ++ss) {
    const int cur = ss % 3;
    stage(ktfor(ss + 2), (ss + 2) % 3);          // 4 gl_lds, depth-2 prefetch

    asm volatile("s_waitcnt vmcnt(8)" ::: "memory");  // oldest batch (this step's) done
    __builtin_amdgcn_s_barrier();
    __builtin_amdgcn_sched_barrier(0);

    const int kt = ktfor(ss);
    if (!(kt == 2 * sup + 1 && w < 2)) {
      const unsigned short* Kb = &Kl[cur][0];
      const unsigned short* Vb = &Vl[cur][0];

      s16x8 kf[8];
      #pragma unroll
      for (int kc = 0; kc < 8; ++kc)
        kf[kc] = *(const s16x8*)&Kb[((kc * 4 + grp) * 16 + lr) * 8];

      f32x4 sc[2][4];
      #pragma unroll
      for (int q2 = 0; q2 < 2; ++q2) {
        #pragma unroll
        for (int kvt = 0; kvt < 4; ++kvt) {
          f32x4 a = __builtin_amdgcn_mfma_f32_16x16x32_bf16(kf[kvt * 2 + 0], qf[q2][0], minit, 0, 0, 0);
          a = __builtin_amdgcn_mfma_f32_16x16x32_bf16(kf[kvt * 2 + 1], qf[q2][1], a, 0, 0, 0);
          sc[q2][kvt] = a;
        }
      }

      if (kt >= 2 * sup) {
        const int kvb0 = kt * 64;
        #pragma unroll
        for (int q2 = 0; q2 < 2; ++q2) {
          const int qrow = sup * 128 + w * 32 + q2 * 16 + lr;
          #pragma unroll
          for (int kvt = 0; kvt < 4; ++kvt)
            #pragma unroll
            for (int e = 0; e < 4; ++e)
              if ((kvb0 + kvt * 16 + grp * 4 + e) > qrow) sc[q2][kvt][e] += -1.0e9f;
        }
      }

      #pragma unroll
      for (int q2 = 0; q2 < 2; ++q2)
        #pragma unroll
        for (int kvt = 0; kvt < 4; ++kvt)
          #pragma unroll
          for (int e = 0; e < 4; ++e)
            sc[q2][kvt][e] = fexp2(sc[q2][kvt][e]);

      s16x8 pf[2][2];
      #pragma unroll
      for (int q2 = 0; q2 < 2; ++q2) {
        #pragma unroll
        for (int kap = 0; kap < 2; ++kap) {
          union { u32 wd[4]; s16x8 v; } pu;
          pu.wd[0] = cvtpk(sc[q2][2 * kap][0], sc[q2][2 * kap][1]);
          pu.wd[1] = cvtpk(sc[q2][2 * kap][2], sc[q2][2 * kap][3]);
          pu.wd[2] = cvtpk(sc[q2][2 * kap + 1][0], sc[q2][2 * kap + 1][1]);
          pu.wd[3] = cvtpk(sc[q2][2 * kap + 1][2], sc[q2][2 * kap + 1][3]);
          pf[q2][kap] = pu.v;
        }
      }

      #pragma unroll
      for (int m2 = 0; m2 < 4; ++m2) {
        #pragma unroll
        for (int kap = 0; kap < 2; ++kap) {
          s16x8 vfr = *(const s16x8*)&Vb[((m2 * 2 + kap) * 64 + l) * 8];
          cacc[0][m2] = __builtin_amdgcn_mfma_f32_16x16x32_bf16(vfr, pf[0][kap], cacc[0][m2], 0, 0, 0);
          cacc[1][m2] = __builtin_amdgcn_mfma_f32_16x16x32_bf16(vfr, pf[1][kap], cacc[1][m2], 0, 0, 0);
        }
      }
      #pragma unroll
      for (int q2 = 0; q2 < 2; ++q2) {
        lacc[q2] = __builtin_amdgcn_mfma_f32_16x16x32_bf16(ones, pf[q2][0], lacc[q2], 0, 0, 0);
        lacc[q2] = __builtin_amdgcn_mfma_f32_16x16x32_bf16(ones, pf[q2][1], lacc[q2], 0, 0, 0);
      }
    }

    if (role == 0 && ss == phA_last) {   // phase-A epilogue + switch to supertile B
      #pragma unroll
      for (int q2 = 0; q2 < 2; ++q2) {
        const int rowg = sup * 128 + w * 32 + q2 * 16 + lr;
        float* np_ = num0 + ((size_t)((b << 12) + rowg)) * 256 + h * 64;
        #pragma unroll
        for (int m2 = 0; m2 < 4; ++m2) {
          *(f32x4*)&np_[m2 * 16 + grp * 4] = cacc[q2][m2];
          cacc[q2][m2] = (f32x4){0.f, 0.f, 0.f, 0.f};
        }
        if (grp == 0) lb0[(bh << 12) + rowg] = lacc[q2][0];
        lacc[q2] = (f32x4){0.f, 0.f, 0.f, 0.f};
      }
      sup = 31 - pr;
      #pragma unroll
      for (int q2 = 0; q2 < 2; ++q2) {
        const unsigned short* qp = qpb + (size_t)(sup * 128 + w * 32 + q2 * 16 + lr) * KK;
        qf[q2][0] = *(const s16x8*)(qp + grp * 8);
        qf[q2][1] = *(const s16x8*)(qp + 32 + grp * 8);
      }
    }

    __builtin_amdgcn_sched_barrier(0);
    __builtin_amdgcn_s_barrier();        // all waves done reading buf before reuse
  }

  if (role == 0) {
    #pragma unroll
    for (int q2 = 0; q2 < 2; ++q2) {
      const int rowg = sup * 128 + w * 32 + q2 * 16 + lr;
      float* np_ = num0 + ((size_t)((b << 12) + rowg)) * 256 + h * 64;
      #pragma unroll
      for (int m2 = 0; m2 < 4; ++m2)
        *(f32x4*)&np_[m2 * 16 + grp * 4] = cacc[q2][m2];
      if (grp == 0) lb0[(bh << 12) + rowg] = lacc[q2][0];
    }
  } else {
    #pragma unroll
    for (int q2 = 0; q2 < 2; ++q2) {
      const int rowg = sup * 128 + w * 32 + q2 * 16 + lr;   // >= 2048
      float* np_ = num1 + ((size_t)((b << 11) + (rowg - 2048))) * 256 + h * 64;
      #pragma unroll
      for (int m2 = 0; m2 < 4; ++m2)
        *(f32x4*)&np_[m2 * 16 + grp * 4] = cacc[q2][m2];
      if (grp == 0) lb1[(bh << 11) + (rowg - 2048)] = lacc[q2][0];
    }
  }
}

// ---------------- Kernel 3: output projection + residual + LayerNorm (MFMA) ----------------
__global__ __launch_bounds__(256, 4) void oproj_ln(
    const float* __restrict__ num0, const float* __restrict__ num1,
    const float* __restrict__ lb0, const float* __restrict__ lb1,
    const unsigned short* __restrict__ Wot,
    const float* __restrict__ bo, const float* __restrict__ query,
    const float* __restrict__ gamma, const float* __restrict__ beta,
    float* __restrict__ out)
{
  __shared__ __align__(16) float redS[32][4];
  __shared__ __align__(16) float redQ[32][4];

  const int t = threadIdx.x;
  const int w = t >> 6, l = t & 63, lr = l & 15, grp = l >> 4;
  const long r0 = (long)blockIdx.x * 32;
  const int n0c = w * 64;
  const int b = (int)(r0 >> 12);
  const bool heavy = ((r0 >> 11) & 1) != 0;

  float invl[2][4];
  #pragma unroll
  for (int mt = 0; mt < 2; ++mt) {
    const int grow = (int)r0 + mt * 16 + lr;
    #pragma unroll
    for (int h = 0; h < 4; ++h) {
      float lv = lb0[((b * 4 + h) << 12) + (grow & 4095)];
      if (heavy) lv += lb1[((b * 4 + h) << 11) + (grow & 2047)];
      invl[mt][h] = 1.0f / lv;
    }
  }

  f32x4 acc[2][4] = {};

  #pragma unroll
  for (int k0 = 0; k0 < 256; k0 += 32) {
    s16x8 bfr[2];
    #pragma unroll
    for (int mt = 0; mt < 2; ++mt) {
      const int grow = (int)r0 + mt * 16 + lr;
      const int c = k0 + grp * 8;
      const float* p0 = num0 + (size_t)grow * 256 + c;
      f32x4 a0 = *(const f32x4*)p0;
      f32x4 a1 = *(const f32x4*)(p0 + 4);
      if (heavy) {
        const float* p1 = num1 + ((size_t)((b << 11) + (grow & 2047))) * 256 + c;
        a0 += *(const f32x4*)p1;
        a1 += *(const f32x4*)(p1 + 4);
      }
      const float iv = invl[mt][k0 >> 6];
      a0 *= iv; a1 *= iv;
      union { u32 wd[4]; s16x8 v; } bb;
      bb.wd[0] = cvtpk(a0[0], a0[1]);
      bb.wd[1] = cvtpk(a0[2], a0[3]);
      bb.wd[2] = cvtpk(a1[0], a1[1]);
      bb.wd[3] = cvtpk(a1[2], a1[3]);
      bfr[mt] = bb.v;
    }
    #pragma unroll
    for (int nt = 0; nt < 4; ++nt) {
      s16x8 af = *(const s16x8*)(Wot + (size_t)(n0c + nt * 16 + lr) * 256 + k0 + grp * 8);
      acc[0][nt] = __builtin_amdgcn_mfma_f32_16x16x32_bf16(af, bfr[0], acc[0][nt], 0, 0, 0);
      acc[1][nt] = __builtin_amdgcn_mfma_f32_16x16x32_bf16(af, bfr[1], acc[1][nt], 0, 0, 0);
    }
  }

  float sm[2] = {0.f, 0.f}, sq[2] = {0.f, 0.f};
  #pragma unroll
  for (int mt = 0; mt < 2; ++mt) {
    const long s = r0 + mt * 16 + lr;
    #pragma unroll
    for (int nt = 0; nt < 4; ++nt) {
      const int n = n0c + nt * 16 + grp * 4;
      f32x4 v = acc[mt][nt] + *(const f32x4*)&bo[n] + *(const f32x4*)&query[s * 256 + n];
      acc[mt][nt] = v;
      sm[mt] += v[0] + v[1] + v[2] + v[3];
      sq[mt] += v[0]*v[0] + v[1]*v[1] + v[2]*v[2] + v[3]*v[3];
    }
    sm[mt] += __shfl_xor(sm[mt], 16); sm[mt] += __shfl_xor(sm[mt], 32);
    sq[mt] += __shfl_xor(sq[mt], 16); sq[mt] += __shfl_xor(sq[mt], 32);
  }
  if (grp == 0) {
    redS[0 * 16 + lr][w] = sm[0]; redQ[0 * 16 + lr][w] = sq[0];
    redS[1 * 16 + lr][w] = sm[1]; redQ[1 * 16 + lr][w] = sq[1];
  }
  __syncthreads();

  #pragma unroll
  for (int mt = 0; mt < 2; ++mt) {
    f32x4 s4 = *(const f32x4*)&redS[mt * 16 + lr][0];
    f32x4 q4 = *(const f32x4*)&redQ[mt * 16 + lr][0];
    const float tot = s4[0] + s4[1] + s4[2] + s4[3];
    const float tq  = q4[0] + q4[1] + q4[2] + q4[3];
    const float mu  = tot * 0.00390625f;
    const float var = tq * 0.00390625f - mu * mu;
    const float rs  = rsqrtf(var + 1.0e-3f);
    const long s = r0 + mt * 16 + lr;
    #pragma unroll
    for (int nt = 0; nt < 4; ++nt) {
      const int n = n0c + nt * 16 + grp * 4;
      f32x4 g = *(const f32x4*)&gamma[n];
      f32x4 bt = *(const f32x4*)&beta[n];
      f32x4 o = (acc[mt][nt] - mu) * rs * g + bt;
      *(f32x4*)&out[s * 256 + n] = o;
    }
  }
}

extern "C" void kernel_launch(void* const* d_in, const int* in_sizes, int n_in,
                              void* d_out, int out_size, void* d_ws, size_t ws_size,
                              hipStream_t stream) {
  const float* query = (const float*)d_in[0];
  const float* value = (const float*)d_in[1];
  const float* Wq    = (const float*)d_in[2];
  const float* bq    = (const float*)d_in[3];
  const float* Wk    = (const float*)d_in[4];
  const float* bk    = (const float*)d_in[5];
  const float* Wv    = (const float*)d_in[6];
  const float* bv    = (const float*)d_in[7];
  const float* Wo    = (const float*)d_in[8];
  const float* bo    = (const float*)d_in[9];
  const float* gamma = (const float*)d_in[10];
  const float* beta  = (const float*)d_in[11];
  float* out = (float*)d_out;

  char* ws = (char*)d_ws;
  unsigned short* qb   = (unsigned short*)ws;                         //  8 MiB bf16 [bh][s][dk]
  unsigned short* kbs  = (unsigned short*)(ws + ((size_t)8  << 20));  //  8 MiB bf16 chunked K
  unsigned short* vts  = (unsigned short*)(ws + ((size_t)16 << 20));  //  8 MiB bf16 chunked V^T
  float* num0          = (float*)(ws + ((size_t)24 << 20));           // 16 MiB f32
  float* num1          = (float*)(ws + ((size_t)40 << 20));           //  8 MiB f32 (heavy rows)
  float* lb0           = (float*)(ws + ((size_t)48 << 20));           // 256 KiB f32
  float* lb1           = (float*)(ws + ((size_t)48 << 20) + ((size_t)256 << 10)); // 128 KiB
  unsigned short* Wt   = (unsigned short*)(ws + ((size_t)48 << 20) + ((size_t)512 << 10)); // 384 KiB
  unsigned short* Wot  = Wt + (size_t)768 * 256;                      // 128 KiB

  wprep<<<64, 256, 0, stream>>>(Wq, Wk, Wv, Wo, Wt, Wot);
  qkv_mfma<<<512, 256, 0, stream>>>(query, value, Wt, bq, bk, bv, qb, kbs, vts);
  attn<<<512, 256, 0, stream>>>(qb, kbs, vts, num0, num1, lb0, lb1);
  oproj_ln<<<512, 256, 0, stream>>>(num0, num1, lb0, lb1, Wot, bo, query, gamma, beta, out);
}

// Round 12
// 110.571 us; speedup vs baseline: 1.0552x; 1.0552x over previous
//
#include <hip/hip_runtime.h>
#include <hip/hip_bf16.h>
#include <stdint.h>

#define SS 4096
#define DD 256
#define HH 4
#define KK 64
#define ALPHA 0.18033688011112042f  // 0.125 * log2(e)

typedef float f32x4 __attribute__((ext_vector_type(4)));
typedef short s16x8 __attribute__((ext_vector_type(8)));
typedef unsigned int u32;

__device__ __forceinline__ unsigned short f2bf(float x) {
  union { float f; unsigned u; } v; v.f = x;
  unsigned r = v.u + 0x7fffu + ((v.u >> 16) & 1u);
  return (unsigned short)(r >> 16);
}

__device__ __forceinline__ u32 cvtpk(float lo, float hi) {
  u32 r;
  asm("v_cvt_pk_bf16_f32 %0, %1, %2" : "=v"(r) : "v"(lo), "v"(hi));
  return r;
}

// hardware 2^x via compiler intrinsic (hazard-safe, single v_exp_f32)
#define fexp2(x) __builtin_amdgcn_exp2f(x)

__device__ __forceinline__ void gl_lds16(const unsigned short* g, unsigned short* l) {
  __builtin_amdgcn_global_load_lds(
      (const __attribute__((address_space(1))) u32*)g,
      (__attribute__((address_space(3))) u32*)l, 16, 0, 0);
}

// accumulate 8 bf16 (as shorts) into two f32x4
__device__ __forceinline__ void acc8(const unsigned short* p, f32x4& a0, f32x4& a1) {
  s16x8 v = *(const s16x8*)p;
  union { u32 u; float f; } c;
  #pragma unroll
  for (int j = 0; j < 4; ++j) { c.u = ((u32)(unsigned short)v[j]) << 16; a0[j] += c.f; }
  #pragma unroll
  for (int j = 0; j < 4; ++j) { c.u = ((u32)(unsigned short)v[4 + j]) << 16; a1[j] += c.f; }
}

// ---------------- Kernel 0: weight prep ----------------
__global__ void wprep(const float* __restrict__ Wq, const float* __restrict__ Wk,
                      const float* __restrict__ Wv, const float* __restrict__ Wo,
                      unsigned short* __restrict__ Wt, unsigned short* __restrict__ Wot)
{
  const int blk = blockIdx.x, t = threadIdx.x;
  const int rsub = t >> 4;
  const int c0 = (t & 15) * 16;
  if (blk < 48) {
    const int n = blk * 16 + rsub;               // 0..767
    const float* W = (n < 256) ? Wq : ((n < 512) ? Wk : Wv);
    const int nn = n & 255;
    const float sc = (n < 256) ? ALPHA : 1.0f;
    for (int c = c0; c < c0 + 16; ++c)
      Wt[(size_t)n * 256 + c] = f2bf(sc * W[(size_t)c * 256 + nn]);
  } else {
    const int d = (blk - 48) * 16 + rsub;        // 0..255
    for (int c = c0; c < c0 + 16; ++c)
      Wot[(size_t)d * 256 + c] = f2bf(Wo[(size_t)c * 256 + d]);
  }
}

// ---------------- Kernel 1: QKV projection (r10 version: per-matrix blocks) ----------------
__global__ __launch_bounds__(256, 3) void qkv_mfma(
    const float* __restrict__ query, const float* __restrict__ value,
    const unsigned short* __restrict__ Wt,
    const float* __restrict__ bq, const float* __restrict__ bk,
    const float* __restrict__ bv,
    unsigned short* __restrict__ qb, unsigned short* __restrict__ kbs,
    unsigned short* __restrict__ vts)
{
  __shared__ __align__(16) unsigned short Xs[64 * 256];   // 32 KB, swizzled

  const int t = threadIdx.x;
  const int w = t >> 6, l = t & 63, lr = l & 15, grp = l >> 4;
  const int mat = (int)(blockIdx.x % 3u);
  const int rb  = (int)(blockIdx.x / 3u);
  const long r0 = (long)rb * 64;

  const float* X = (mat == 0) ? query : value;

  {
    const int row = t >> 2;
    const int c0s = (t & 3) * 64;
    const float* xp = X + (r0 + row) * 256 + c0s;
    const int sw = (row & 7) << 3;
    #pragma unroll
    for (int g = 0; g < 8; ++g) {
      f32x4 x0 = *(const f32x4*)(xp + g * 8);
      f32x4 x1 = *(const f32x4*)(xp + g * 8 + 4);
      union { u32 wd[4]; s16x8 v; } bb;
      bb.wd[0] = cvtpk(x0[0], x0[1]);
      bb.wd[1] = cvtpk(x0[2], x0[3]);
      bb.wd[2] = cvtpk(x1[0], x1[1]);
      bb.wd[3] = cvtpk(x1[2], x1[3]);
      *(s16x8*)&Xs[(row * 256 + c0s + g * 8) ^ sw] = bb.v;
    }
  }
  __syncthreads();

  const int n0 = w * 64;                 // head w
  const int swr = (lr & 7) << 3;

  f32x4 acc[4][4] = {};

  #pragma unroll 2
  for (int k0 = 0; k0 < 256; k0 += 32) {
    s16x8 xf[4];
    #pragma unroll
    for (int mt = 0; mt < 4; ++mt)
      xf[mt] = *(const s16x8*)&Xs[((mt * 16 + lr) * 256 + k0 + grp * 8) ^ swr];
    #pragma unroll
    for (int nt = 0; nt < 4; ++nt) {
      s16x8 af = *(const s16x8*)(Wt + (size_t)(mat * 256 + n0 + nt * 16 + lr) * 256 + k0 + grp * 8);
      if (mat == 2) {
        #pragma unroll
        for (int mt = 0; mt < 4; ++mt)
          acc[mt][nt] = __builtin_amdgcn_mfma_f32_16x16x32_bf16(xf[mt], af, acc[mt][nt], 0, 0, 0);
      } else {
        #pragma unroll
        for (int mt = 0; mt < 4; ++mt)
          acc[mt][nt] = __builtin_amdgcn_mfma_f32_16x16x32_bf16(af, xf[mt], acc[mt][nt], 0, 0, 0);
      }
    }
  }

  const int b  = (int)(r0 >> 12);
  const int s0 = (int)(r0 & 4095);
  const int kt = s0 >> 6;
  const size_t base = (size_t)(b * 4 + w) * (SS * KK) + (size_t)kt * 4096;

  if (mat == 0) {
    #pragma unroll
    for (int nt = 0; nt < 4; ++nt) {
      const int nk = nt * 16 + grp * 4;
      f32x4 bias = *(const f32x4*)&bq[n0 + nk] * ALPHA;
      #pragma unroll
      for (int mt = 0; mt < 4; ++mt) {
        const int s = s0 + mt * 16 + lr;
        f32x4 o = acc[mt][nt] + bias;
        uint2 pk2; pk2.x = cvtpk(o[0], o[1]); pk2.y = cvtpk(o[2], o[3]);
        *(uint2*)&qb[((size_t)(b * 4 + w) * SS + s) * KK + nk] = pk2;
      }
    }
  } else if (mat == 1) {
    #pragma unroll
    for (int nt = 0; nt < 4; ++nt) {
      const int d0 = nt * 16 + grp * 4;
      const int cc = d0 >> 5, grpk = (d0 >> 3) & 3, jlo = d0 & 7;
      f32x4 bias = *(const f32x4*)&bk[n0 + d0];
      #pragma unroll
      for (int mt = 0; mt < 4; ++mt) {
        const int chunk = ((mt * 2 + cc) * 4 + grpk) * 16 + lr;
        f32x4 o = acc[mt][nt] + bias;
        uint2 pk2; pk2.x = cvtpk(o[0], o[1]); pk2.y = cvtpk(o[2], o[3]);
        *(uint2*)&kbs[base + chunk * 8 + jlo] = pk2;
      }
    }
  } else {
    #pragma unroll
    for (int nt = 0; nt < 4; ++nt) {
      const float bvn = bv[n0 + nt * 16 + lr];
      #pragma unroll
      for (int mt = 0; mt < 4; ++mt) {
        const int cb = (nt * 2 + (mt >> 1)) * 64 + grp * 16 + lr;
        f32x4 o = acc[mt][nt] + bvn;
        uint2 pk2; pk2.x = cvtpk(o[0], o[1]); pk2.y = cvtpk(o[2], o[3]);
        *(uint2*)&vts[base + (size_t)cb * 8 + (mt & 1) * 4] = pk2;
      }
    }
  }
}

// ---------------- Kernel 2: causal flash attention (kv-half waves, 4 blocks/CU) ----------------
// 1024 blocks x 256 thr. Block = 64 q-rows; waves = (qg = w>>1) x (kh = w&1):
// wave computes its 32-kv half of each 64-row KV tile (4+4 ds_read_b128,
// 18 MFMA) -> per-wave chain halves, per-block LDS 32 KB -> 4 blocks/CU
// (16 waves/CU, 4/SIMD TLP). bh = i&15, pr = (i>>4)&31, role = (i>>9)&1.
// role0: supertile pr full (pr+1 tiles) then B=63-pr tiles [0,32-pr) (33 steps);
// role1: B tiles [32-pr, 64-pr) (32 steps). Fixed-max softmax P=exp2(s-16);
// partials (num bf16, l f32) per wave -> slot role*2+kh, merged in oproj.
__global__ __launch_bounds__(256, 4) void attn(
    const unsigned short* __restrict__ qb,
    const unsigned short* __restrict__ kbs,
    const unsigned short* __restrict__ vts,
    unsigned short* __restrict__ ns0, unsigned short* __restrict__ ns1,
    unsigned short* __restrict__ ns2, unsigned short* __restrict__ ns3,
    float* __restrict__ lb0, float* __restrict__ lb1,
    float* __restrict__ lb2, float* __restrict__ lb3)
{
  __shared__ __align__(16) unsigned short Kl[2][4096];
  __shared__ __align__(16) unsigned short Vl[2][4096];

  const int t = threadIdx.x;
  const int w = t >> 6, l = t & 63, lr = l & 15, grp = l >> 4;
  const int qg = w >> 1, kh = w & 1;

  const int i    = blockIdx.x;
  const int bh   = i & 15;
  const int pr   = (i >> 4) & 31;
  const int role = (i >> 9) & 1;
  const int b = bh >> 2, h = bh & 3;

  const unsigned short* kbase = kbs + (size_t)bh * (SS * KK);
  const unsigned short* vbase = vts + (size_t)bh * (SS * KK);
  const unsigned short* qpb   = qb  + (size_t)bh * (SS * KK);

  int sup = (role == 0) ? pr : (63 - pr);
  const int nsteps = 33 - role;

  s16x8 qf[2][2];
  #pragma unroll
  for (int q2 = 0; q2 < 2; ++q2) {
    const unsigned short* qp = qpb + (size_t)(sup * 64 + qg * 32 + q2 * 16 + lr) * KK;
    qf[q2][0] = *(const s16x8*)(qp + grp * 8);
    qf[q2][1] = *(const s16x8*)(qp + 32 + grp * 8);
  }

  s16x8 ones;
  #pragma unroll
  for (int e = 0; e < 8; ++e) ones[e] = (short)0x3F80;   // bf16 1.0
  const f32x4 minit = {-16.f, -16.f, -16.f, -16.f};

  f32x4 cacc[2][4] = {};
  f32x4 lacc[2] = {};

  const int off0 = (w * 64 + l) * 8;
  const int off1 = ((4 + w) * 64 + l) * 8;

  auto ktfor = [&](int s) {
    return (role == 0) ? ((s <= pr) ? s : (s - (pr + 1))) : (32 - pr + s);
  };
  auto stage = [&](int kt, int bi) {
    const unsigned short* ks = kbase + (size_t)kt * 4096;
    const unsigned short* vs = vbase + (size_t)kt * 4096;
    gl_lds16(ks + off0, &Kl[bi][w * 512]);
    gl_lds16(ks + off1, &Kl[bi][(4 + w) * 512]);
    gl_lds16(vs + off0, &Vl[bi][w * 512]);
    gl_lds16(vs + off1, &Vl[bi][(4 + w) * 512]);
  };

  stage(ktfor(0), 0);
  __syncthreads();

  for (int ss = 0; ss < nsteps; ++ss) {
    const int cur = ss & 1;
    if (ss + 1 < nsteps) stage(ktfor(ss + 1), cur ^ 1);

    const int kt = ktfor(ss);
    const unsigned short* Kb = &Kl[cur][0];
    const unsigned short* Vb = &Vl[cur][0];

    // K fragments for this wave's kv-half: kc = kh*4 + j
    s16x8 kf[4];
    #pragma unroll
    for (int j = 0; j < 4; ++j)
      kf[j] = *(const s16x8*)&Kb[(((kh * 4 + j) * 4 + grp) * 16 + lr) * 8];

    // QK^T: S^T D[kv][q], kv in this wave's half; C-init = -16
    f32x4 sc[2][2];
    #pragma unroll
    for (int q2 = 0; q2 < 2; ++q2) {
      #pragma unroll
      for (int tt = 0; tt < 2; ++tt) {
        f32x4 a = __builtin_amdgcn_mfma_f32_16x16x32_bf16(kf[tt * 2 + 0], qf[q2][0], minit, 0, 0, 0);
        a = __builtin_amdgcn_mfma_f32_16x16x32_bf16(kf[tt * 2 + 1], qf[q2][1], a, 0, 0, 0);
        sc[q2][tt] = a;
      }
    }

    // causal mask: only on the diagonal tile (kt == sup)
    if (kt == sup) {
      #pragma unroll
      for (int q2 = 0; q2 < 2; ++q2) {
        const int qloc = qg * 32 + q2 * 16 + lr;
        #pragma unroll
        for (int tt = 0; tt < 2; ++tt)
          #pragma unroll
          for (int e = 0; e < 4; ++e)
            if (((kh * 2 + tt) * 16 + grp * 4 + e) > qloc) sc[q2][tt][e] += -1.0e9f;
      }
    }

    #pragma unroll
    for (int q2 = 0; q2 < 2; ++q2)
      #pragma unroll
      for (int tt = 0; tt < 2; ++tt)
        #pragma unroll
        for (int e = 0; e < 4; ++e)
          sc[q2][tt][e] = fexp2(sc[q2][tt][e]);

    // pack P (kap = kh): kv = kh*32 + (jj>>2)*16 + grp*4 + (jj&3)
    s16x8 pf[2];
    #pragma unroll
    for (int q2 = 0; q2 < 2; ++q2) {
      union { u32 wd[4]; s16x8 v; } pu;
      pu.wd[0] = cvtpk(sc[q2][0][0], sc[q2][0][1]);
      pu.wd[1] = cvtpk(sc[q2][0][2], sc[q2][0][3]);
      pu.wd[2] = cvtpk(sc[q2][1][0], sc[q2][1][1]);
      pu.wd[3] = cvtpk(sc[q2][1][2], sc[q2][1][3]);
      pf[q2] = pu.v;
    }

    // PV + row-sum for this kv-half
    #pragma unroll
    for (int m2 = 0; m2 < 4; ++m2) {
      s16x8 vfr = *(const s16x8*)&Vb[((m2 * 2 + kh) * 64 + l) * 8];
      cacc[0][m2] = __builtin_amdgcn_mfma_f32_16x16x32_bf16(vfr, pf[0], cacc[0][m2], 0, 0, 0);
      cacc[1][m2] = __builtin_amdgcn_mfma_f32_16x16x32_bf16(vfr, pf[1], cacc[1][m2], 0, 0, 0);
    }
    lacc[0] = __builtin_amdgcn_mfma_f32_16x16x32_bf16(ones, pf[0], lacc[0], 0, 0, 0);
    lacc[1] = __builtin_amdgcn_mfma_f32_16x16x32_bf16(ones, pf[1], lacc[1], 0, 0, 0);

    // role0 phase switch after finishing supertile A
    if (role == 0 && ss == pr) {
      unsigned short* nsl = kh ? ns1 : ns0;
      float* lbl = kh ? lb1 : lb0;
      #pragma unroll
      for (int q2 = 0; q2 < 2; ++q2) {
        const int rowg = sup * 64 + qg * 32 + q2 * 16 + lr;
        unsigned short* np_ = nsl + ((size_t)((b << 12) + rowg)) * 256 + h * 64;
        #pragma unroll
        for (int m2 = 0; m2 < 4; ++m2) {
          uint2 pk2; pk2.x = cvtpk(cacc[q2][m2][0], cacc[q2][m2][1]);
          pk2.y = cvtpk(cacc[q2][m2][2], cacc[q2][m2][3]);
          *(uint2*)&np_[m2 * 16 + grp * 4] = pk2;
          cacc[q2][m2] = (f32x4){0.f, 0.f, 0.f, 0.f};
        }
        if (grp == 0) lbl[(bh << 12) + rowg] = lacc[q2][0];
        lacc[q2] = (f32x4){0.f, 0.f, 0.f, 0.f};
      }
      sup = 63 - pr;
      #pragma unroll
      for (int q2 = 0; q2 < 2; ++q2) {
        const unsigned short* qp = qpb + (size_t)(sup * 64 + qg * 32 + q2 * 16 + lr) * KK;
        qf[q2][0] = *(const s16x8*)(qp + grp * 8);
        qf[q2][1] = *(const s16x8*)(qp + 32 + grp * 8);
      }
    }
    __syncthreads();
  }

  // final epilogue: role0 -> slots 0/1 (full arrays, heavy rows); role1 -> slots 2/3
  if (role == 0) {
    unsigned short* nsl = kh ? ns1 : ns0;
    float* lbl = kh ? lb1 : lb0;
    #pragma unroll
    for (int q2 = 0; q2 < 2; ++q2) {
      const int rowg = sup * 64 + qg * 32 + q2 * 16 + lr;
      unsigned short* np_ = nsl + ((size_t)((b << 12) + rowg)) * 256 + h * 64;
      #pragma unroll
      for (int m2 = 0; m2 < 4; ++m2) {
        uint2 pk2; pk2.x = cvtpk(cacc[q2][m2][0], cacc[q2][m2][1]);
        pk2.y = cvtpk(cacc[q2][m2][2], cacc[q2][m2][3]);
        *(uint2*)&np_[m2 * 16 + grp * 4] = pk2;
      }
      if (grp == 0) lbl[(bh << 12) + rowg] = lacc[q2][0];
    }
  } else {
    unsigned short* nsl = kh ? ns3 : ns2;
    float* lbl = kh ? lb3 : lb2;
    #pragma unroll
    for (int q2 = 0; q2 < 2; ++q2) {
      const int rowg = sup * 64 + qg * 32 + q2 * 16 + lr;   // >= 2048
      unsigned short* np_ = nsl + ((size_t)((b << 11) + (rowg - 2048))) * 256 + h * 64;
      #pragma unroll
      for (int m2 = 0; m2 < 4; ++m2) {
        uint2 pk2; pk2.x = cvtpk(cacc[q2][m2][0], cacc[q2][m2][1]);
        pk2.y = cvtpk(cacc[q2][m2][2], cacc[q2][m2][3]);
        *(uint2*)&np_[m2 * 16 + grp * 4] = pk2;
      }
      if (grp == 0) lbl[(bh << 11) + (rowg - 2048)] = lacc[q2][0];
    }
  }
}

// ---------------- Kernel 3: output projection + residual + LayerNorm (MFMA) ----------------
__global__ __launch_bounds__(256, 4) void oproj_ln(
    const unsigned short* __restrict__ ns0, const unsigned short* __restrict__ ns1,
    const unsigned short* __restrict__ ns2, const unsigned short* __restrict__ ns3,
    const float* __restrict__ lb0, const float* __restrict__ lb1,
    const float* __restrict__ lb2, const float* __restrict__ lb3,
    const unsigned short* __restrict__ Wot,
    const float* __restrict__ bo, const float* __restrict__ query,
    const float* __restrict__ gamma, const float* __restrict__ beta,
    float* __restrict__ out)
{
  __shared__ __align__(16) float redS[32][4];
  __shared__ __align__(16) float redQ[32][4];

  const int t = threadIdx.x;
  const int w = t >> 6, l = t & 63, lr = l & 15, grp = l >> 4;
  const long r0 = (long)blockIdx.x * 32;
  const int n0c = w * 64;
  const int b = (int)(r0 >> 12);
  const bool heavy = ((r0 >> 11) & 1) != 0;

  float invl[2][4];
  #pragma unroll
  for (int mt = 0; mt < 2; ++mt) {
    const int grow = (int)r0 + mt * 16 + lr;
    #pragma unroll
    for (int h = 0; h < 4; ++h) {
      const int i12 = ((b * 4 + h) << 12) + (grow & 4095);
      float lv = lb0[i12] + lb1[i12];
      if (heavy) {
        const int i11 = ((b * 4 + h) << 11) + (grow & 2047);
        lv += lb2[i11] + lb3[i11];
      }
      invl[mt][h] = 1.0f / lv;
    }
  }

  f32x4 acc[2][4] = {};

  #pragma unroll
  for (int k0 = 0; k0 < 256; k0 += 32) {
    s16x8 bfr[2];
    #pragma unroll
    for (int mt = 0; mt < 2; ++mt) {
      const int grow = (int)r0 + mt * 16 + lr;
      const int c = k0 + grp * 8;
      f32x4 a0 = {0.f, 0.f, 0.f, 0.f}, a1 = {0.f, 0.f, 0.f, 0.f};
      const size_t o01 = (size_t)grow * 256 + c;
      acc8(ns0 + o01, a0, a1);
      acc8(ns1 + o01, a0, a1);
      if (heavy) {
        const size_t o23 = ((size_t)((b << 11) + (grow & 2047))) * 256 + c;
        acc8(ns2 + o23, a0, a1);
        acc8(ns3 + o23, a0, a1);
      }
      const float iv = invl[mt][k0 >> 6];
      a0 *= iv; a1 *= iv;
      union { u32 wd[4]; s16x8 v; } bb;
      bb.wd[0] = cvtpk(a0[0], a0[1]);
      bb.wd[1] = cvtpk(a0[2], a0[3]);
      bb.wd[2] = cvtpk(a1[0], a1[1]);
      bb.wd[3] = cvtpk(a1[2], a1[3]);
      bfr[mt] = bb.v;
    }
    #pragma unroll
    for (int nt = 0; nt < 4; ++nt) {
      s16x8 af = *(const s16x8*)(Wot + (size_t)(n0c + nt * 16 + lr) * 256 + k0 + grp * 8);
      acc[0][nt] = __builtin_amdgcn_mfma_f32_16x16x32_bf16(af, bfr[0], acc[0][nt], 0, 0, 0);
      acc[1][nt] = __builtin_amdgcn_mfma_f32_16x16x32_bf16(af, bfr[1], acc[1][nt], 0, 0, 0);
    }
  }

  float sm[2] = {0.f, 0.f}, sq[2] = {0.f, 0.f};
  #pragma unroll
  for (int mt = 0; mt < 2; ++mt) {
    const long s = r0 + mt * 16 + lr;
    #pragma unroll
    for (int nt = 0; nt < 4; ++nt) {
      const int n = n0c + nt * 16 + grp * 4;
      f32x4 v = acc[mt][nt] + *(const f32x4*)&bo[n] + *(const f32x4*)&query[s * 256 + n];
      acc[mt][nt] = v;
      sm[mt] += v[0] + v[1] + v[2] + v[3];
      sq[mt] += v[0]*v[0] + v[1]*v[1] + v[2]*v[2] + v[3]*v[3];
    }
    sm[mt] += __shfl_xor(sm[mt], 16); sm[mt] += __shfl_xor(sm[mt], 32);
    sq[mt] += __shfl_xor(sq[mt], 16); sq[mt] += __shfl_xor(sq[mt], 32);
  }
  if (grp == 0) {
    redS[0 * 16 + lr][w] = sm[0]; redQ[0 * 16 + lr][w] = sq[0];
    redS[1 * 16 + lr][w] = sm[1]; redQ[1 * 16 + lr][w] = sq[1];
  }
  __syncthreads();

  #pragma unroll
  for (int mt = 0; mt < 2; ++mt) {
    f32x4 s4 = *(const f32x4*)&redS[mt * 16 + lr][0];
    f32x4 q4 = *(const f32x4*)&redQ[mt * 16 + lr][0];
    const float tot = s4[0] + s4[1] + s4[2] + s4[3];
    const float tq  = q4[0] + q4[1] + q4[2] + q4[3];
    const float mu  = tot * 0.00390625f;
    const float var = tq * 0.00390625f - mu * mu;
    const float rs  = rsqrtf(var + 1.0e-3f);
    const long s = r0 + mt * 16 + lr;
    #pragma unroll
    for (int nt = 0; nt < 4; ++nt) {
      const int n = n0c + nt * 16 + grp * 4;
      f32x4 g = *(const f32x4*)&gamma[n];
      f32x4 bt = *(const f32x4*)&beta[n];
      f32x4 o = (acc[mt][nt] - mu) * rs * g + bt;
      *(f32x4*)&out[s * 256 + n] = o;
    }
  }
}

extern "C" void kernel_launch(void* const* d_in, const int* in_sizes, int n_in,
                              void* d_out, int out_size, void* d_ws, size_t ws_size,
                              hipStream_t stream) {
  const float* query = (const float*)d_in[0];
  const float* value = (const float*)d_in[1];
  const float* Wq    = (const float*)d_in[2];
  const float* bq    = (const float*)d_in[3];
  const float* Wk    = (const float*)d_in[4];
  const float* bk    = (const float*)d_in[5];
  const float* Wv    = (const float*)d_in[6];
  const float* bv    = (const float*)d_in[7];
  const float* Wo    = (const float*)d_in[8];
  const float* bo    = (const float*)d_in[9];
  const float* gamma = (const float*)d_in[10];
  const float* beta  = (const float*)d_in[11];
  float* out = (float*)d_out;

  char* ws = (char*)d_ws;
  unsigned short* qb  = (unsigned short*)ws;                          //  8 MiB bf16 [bh][s][dk]
  unsigned short* kbs = (unsigned short*)(ws + ((size_t)8  << 20));   //  8 MiB bf16 chunked K
  unsigned short* vts = (unsigned short*)(ws + ((size_t)16 << 20));   //  8 MiB bf16 chunked V^T
  unsigned short* ns0 = (unsigned short*)(ws + ((size_t)24 << 20));   //  8 MiB bf16 [b*4096][256]
  unsigned short* ns1 = (unsigned short*)(ws + ((size_t)32 << 20));   //  8 MiB
  unsigned short* ns2 = (unsigned short*)(ws + ((size_t)40 << 20));   //  4 MiB bf16 [b*2048][256]
  unsigned short* ns3 = (unsigned short*)(ws + ((size_t)44 << 20));   //  4 MiB
  float* lb0 = (float*)(ws + ((size_t)48 << 20));                     // 256 KiB f32 [16][4096]
  float* lb1 = (float*)(ws + ((size_t)48 << 20) + ((size_t)256 << 10));
  float* lb2 = (float*)(ws + ((size_t)48 << 20) + ((size_t)512 << 10)); // 128 KiB f32 [16][2048]
  float* lb3 = (float*)(ws + ((size_t)48 << 20) + ((size_t)640 << 10));
  unsigned short* Wt  = (unsigned short*)(ws + ((size_t)48 << 20) + ((size_t)768 << 10)); // 384 KiB
  unsigned short* Wot = Wt + (size_t)768 * 256;                       // 128 KiB

  wprep<<<64, 256, 0, stream>>>(Wq, Wk, Wv, Wo, Wt, Wot);
  qkv_mfma<<<768, 256, 0, stream>>>(query, value, Wt, bq, bk, bv, qb, kbs, vts);
  attn<<<1024, 256, 0, stream>>>(qb, kbs, vts, ns0, ns1, ns2, ns3, lb0, lb1, lb2, lb3);
  oproj_ln<<<512, 256, 0, stream>>>(ns0, ns1, ns2, ns3, lb0, lb1, lb2, lb3,
                                    Wot, bo, query, gamma, beta, out);
}

// Round 13
// 100.824 us; speedup vs baseline: 1.1572x; 1.0967x over previous
//
#include <hip/hip_runtime.h>
#include <hip/hip_bf16.h>
#include <stdint.h>

#define SS 4096
#define DD 256
#define HH 4
#define KK 64
#define ALPHA 0.18033688011112042f  // 0.125 * log2(e)

typedef float f32x4 __attribute__((ext_vector_type(4)));
typedef short s16x8 __attribute__((ext_vector_type(8)));
typedef unsigned int u32;

__device__ __forceinline__ unsigned short f2bf(float x) {
  union { float f; unsigned u; } v; v.f = x;
  unsigned r = v.u + 0x7fffu + ((v.u >> 16) & 1u);
  return (unsigned short)(r >> 16);
}

__device__ __forceinline__ u32 cvtpk(float lo, float hi) {
  u32 r;
  asm("v_cvt_pk_bf16_f32 %0, %1, %2" : "=v"(r) : "v"(lo), "v"(hi));
  return r;
}

// hardware 2^x via compiler intrinsic (hazard-safe, single v_exp_f32)
#define fexp2(x) __builtin_amdgcn_exp2f(x)

__device__ __forceinline__ void gl_lds16(const unsigned short* g, unsigned short* l) {
  __builtin_amdgcn_global_load_lds(
      (const __attribute__((address_space(1))) u32*)g,
      (__attribute__((address_space(3))) u32*)l, 16, 0, 0);
}

// accumulate 8 bf16 (as shorts) into two f32x4
__device__ __forceinline__ void acc8(const unsigned short* p, f32x4& a0, f32x4& a1) {
  s16x8 v = *(const s16x8*)p;
  union { u32 u; float f; } c;
  #pragma unroll
  for (int j = 0; j < 4; ++j) { c.u = ((u32)(unsigned short)v[j]) << 16; a0[j] += c.f; }
  #pragma unroll
  for (int j = 0; j < 4; ++j) { c.u = ((u32)(unsigned short)v[4 + j]) << 16; a1[j] += c.f; }
}

// ---------------- Kernel 0: weight prep (256 blocks) ----------------
__global__ void wprep(const float* __restrict__ Wq, const float* __restrict__ Wk,
                      const float* __restrict__ Wv, const float* __restrict__ Wo,
                      unsigned short* __restrict__ Wt, unsigned short* __restrict__ Wot)
{
  const int blk = blockIdx.x, t = threadIdx.x;
  const int rsub = t >> 6;            // 0..3
  const int c0 = (t & 63) * 4;
  if (blk < 192) {
    const int n = blk * 4 + rsub;     // 0..767
    const float* W = (n < 256) ? Wq : ((n < 512) ? Wk : Wv);
    const int nn = n & 255;
    const float sc = (n < 256) ? ALPHA : 1.0f;
    #pragma unroll
    for (int c = c0; c < c0 + 4; ++c)
      Wt[(size_t)n * 256 + c] = f2bf(sc * W[(size_t)c * 256 + nn]);
  } else {
    const int d = (blk - 192) * 4 + rsub;   // 0..255
    #pragma unroll
    for (int c = c0; c < c0 + 4; ++c)
      Wot[(size_t)d * 256 + c] = f2bf(Wo[(size_t)c * 256 + d]);
  }
}

// ---------------- Kernel 1: QKV projection (per-matrix blocks) ----------------
__global__ __launch_bounds__(256, 3) void qkv_mfma(
    const float* __restrict__ query, const float* __restrict__ value,
    const unsigned short* __restrict__ Wt,
    const float* __restrict__ bq, const float* __restrict__ bk,
    const float* __restrict__ bv,
    unsigned short* __restrict__ qb, unsigned short* __restrict__ kbs,
    unsigned short* __restrict__ vts)
{
  __shared__ __align__(16) unsigned short Xs[64 * 256];   // 32 KB, swizzled

  const int t = threadIdx.x;
  const int w = t >> 6, l = t & 63, lr = l & 15, grp = l >> 4;
  const int mat = (int)(blockIdx.x % 3u);
  const int rb  = (int)(blockIdx.x / 3u);
  const long r0 = (long)rb * 64;

  const float* X = (mat == 0) ? query : value;

  {
    const int row = t >> 2;
    const int c0s = (t & 3) * 64;
    const float* xp = X + (r0 + row) * 256 + c0s;
    const int sw = (row & 7) << 3;
    #pragma unroll
    for (int g = 0; g < 8; ++g) {
      f32x4 x0 = *(const f32x4*)(xp + g * 8);
      f32x4 x1 = *(const f32x4*)(xp + g * 8 + 4);
      union { u32 wd[4]; s16x8 v; } bb;
      bb.wd[0] = cvtpk(x0[0], x0[1]);
      bb.wd[1] = cvtpk(x0[2], x0[3]);
      bb.wd[2] = cvtpk(x1[0], x1[1]);
      bb.wd[3] = cvtpk(x1[2], x1[3]);
      *(s16x8*)&Xs[(row * 256 + c0s + g * 8) ^ sw] = bb.v;
    }
  }
  __syncthreads();

  const int n0 = w * 64;                 // head w
  const int swr = (lr & 7) << 3;

  f32x4 acc[4][4] = {};

  #pragma unroll 2
  for (int k0 = 0; k0 < 256; k0 += 32) {
    s16x8 xf[4];
    #pragma unroll
    for (int mt = 0; mt < 4; ++mt)
      xf[mt] = *(const s16x8*)&Xs[((mt * 16 + lr) * 256 + k0 + grp * 8) ^ swr];
    #pragma unroll
    for (int nt = 0; nt < 4; ++nt) {
      s16x8 af = *(const s16x8*)(Wt + (size_t)(mat * 256 + n0 + nt * 16 + lr) * 256 + k0 + grp * 8);
      if (mat == 2) {
        #pragma unroll
        for (int mt = 0; mt < 4; ++mt)
          acc[mt][nt] = __builtin_amdgcn_mfma_f32_16x16x32_bf16(xf[mt], af, acc[mt][nt], 0, 0, 0);
      } else {
        #pragma unroll
        for (int mt = 0; mt < 4; ++mt)
          acc[mt][nt] = __builtin_amdgcn_mfma_f32_16x16x32_bf16(af, xf[mt], acc[mt][nt], 0, 0, 0);
      }
    }
  }

  const int b  = (int)(r0 >> 12);
  const int s0 = (int)(r0 & 4095);
  const int kt = s0 >> 6;
  const size_t base = (size_t)(b * 4 + w) * (SS * KK) + (size_t)kt * 4096;

  if (mat == 0) {
    #pragma unroll
    for (int nt = 0; nt < 4; ++nt) {
      const int nk = nt * 16 + grp * 4;
      f32x4 bias = *(const f32x4*)&bq[n0 + nk] * ALPHA;
      #pragma unroll
      for (int mt = 0; mt < 4; ++mt) {
        const int s = s0 + mt * 16 + lr;
        f32x4 o = acc[mt][nt] + bias;
        uint2 pk2; pk2.x = cvtpk(o[0], o[1]); pk2.y = cvtpk(o[2], o[3]);
        *(uint2*)&qb[((size_t)(b * 4 + w) * SS + s) * KK + nk] = pk2;
      }
    }
  } else if (mat == 1) {
    #pragma unroll
    for (int nt = 0; nt < 4; ++nt) {
      const int d0 = nt * 16 + grp * 4;
      const int cc = d0 >> 5, grpk = (d0 >> 3) & 3, jlo = d0 & 7;
      f32x4 bias = *(const f32x4*)&bk[n0 + d0];
      #pragma unroll
      for (int mt = 0; mt < 4; ++mt) {
        const int chunk = ((mt * 2 + cc) * 4 + grpk) * 16 + lr;
        f32x4 o = acc[mt][nt] + bias;
        uint2 pk2; pk2.x = cvtpk(o[0], o[1]); pk2.y = cvtpk(o[2], o[3]);
        *(uint2*)&kbs[base + chunk * 8 + jlo] = pk2;
      }
    }
  } else {
    #pragma unroll
    for (int nt = 0; nt < 4; ++nt) {
      const float bvn = bv[n0 + nt * 16 + lr];
      #pragma unroll
      for (int mt = 0; mt < 4; ++mt) {
        const int cb = (nt * 2 + (mt >> 1)) * 64 + grp * 16 + lr;
        f32x4 o = acc[mt][nt] + bvn;
        uint2 pk2; pk2.x = cvtpk(o[0], o[1]); pk2.y = cvtpk(o[2], o[3]);
        *(uint2*)&vts[base + (size_t)cb * 8 + (mt & 1) * 4] = pk2;
      }
    }
  }
}

// ---------------- Kernel 2: causal flash attention (kv-half waves, in-block merge) ----------------
// 1024 blocks x 256 thr, 4 blocks/CU. Waves = (qg) x (kh): each wave computes
// its 32-kv half. At epilogues, kh=1 waves dump cacc into the freed Kl/Vl[cur]
// (lane-consecutive, conflict-free) and kh=0 waves write MERGED slots:
// ns0 (all rows: light final / heavy partial) + ns2 (heavy partial), lb0/lb2.
__global__ __launch_bounds__(256, 4) void attn(
    const unsigned short* __restrict__ qb,
    const unsigned short* __restrict__ kbs,
    const unsigned short* __restrict__ vts,
    unsigned short* __restrict__ ns0, unsigned short* __restrict__ ns2,
    float* __restrict__ lb0, float* __restrict__ lb2)
{
  __shared__ __align__(16) unsigned short Kl[2][4096];
  __shared__ __align__(16) unsigned short Vl[2][4096];
  __shared__ float lred[2][2][16];

  const int t = threadIdx.x;
  const int w = t >> 6, l = t & 63, lr = l & 15, grp = l >> 4;
  const int qg = w >> 1, kh = w & 1;

  const int i    = blockIdx.x;
  const int bh   = i & 15;
  const int pr   = (i >> 4) & 31;
  const int role = (i >> 9) & 1;
  const int b = bh >> 2, h = bh & 3;

  const unsigned short* kbase = kbs + (size_t)bh * (SS * KK);
  const unsigned short* vbase = vts + (size_t)bh * (SS * KK);
  const unsigned short* qpb   = qb  + (size_t)bh * (SS * KK);

  int sup = (role == 0) ? pr : (63 - pr);
  const int nsteps = 33 - role;

  s16x8 qf[2][2];
  #pragma unroll
  for (int q2 = 0; q2 < 2; ++q2) {
    const unsigned short* qp = qpb + (size_t)(sup * 64 + qg * 32 + q2 * 16 + lr) * KK;
    qf[q2][0] = *(const s16x8*)(qp + grp * 8);
    qf[q2][1] = *(const s16x8*)(qp + 32 + grp * 8);
  }

  s16x8 ones;
  #pragma unroll
  for (int e = 0; e < 8; ++e) ones[e] = (short)0x3F80;   // bf16 1.0
  const f32x4 minit = {-16.f, -16.f, -16.f, -16.f};

  f32x4 cacc[2][4] = {};
  f32x4 lacc[2] = {};

  const int off0 = (w * 64 + l) * 8;
  const int off1 = ((4 + w) * 64 + l) * 8;

  auto ktfor = [&](int s) {
    return (role == 0) ? ((s <= pr) ? s : (s - (pr + 1))) : (32 - pr + s);
  };
  auto stage = [&](int kt, int bi) {
    const unsigned short* ks = kbase + (size_t)kt * 4096;
    const unsigned short* vs = vbase + (size_t)kt * 4096;
    gl_lds16(ks + off0, &Kl[bi][w * 512]);
    gl_lds16(ks + off1, &Kl[bi][(4 + w) * 512]);
    gl_lds16(vs + off0, &Vl[bi][w * 512]);
    gl_lds16(vs + off1, &Vl[bi][(4 + w) * 512]);
  };

  // kh-merge: kh=1 writes its cacc/lacc into freed Kl/Vl[cur]; kh=0 adds.
  auto merge_kh = [&](int cur) {
    float* mb0 = (float*)&Kl[cur][0];   // q2 = 0
    float* mb1 = (float*)&Vl[cur][0];   // q2 = 1
    if (kh == 1) {
      #pragma unroll
      for (int m2 = 0; m2 < 4; ++m2)
        #pragma unroll
        for (int e = 0; e < 4; ++e) {
          mb0[(m2 * 4 + e) * 128 + qg * 64 + l] = cacc[0][m2][e];
          mb1[(m2 * 4 + e) * 128 + qg * 64 + l] = cacc[1][m2][e];
        }
      if (grp == 0) { lred[qg][0][lr] = lacc[0][0]; lred[qg][1][lr] = lacc[1][0]; }
    }
    __syncthreads();
    if (kh == 0) {
      #pragma unroll
      for (int m2 = 0; m2 < 4; ++m2)
        #pragma unroll
        for (int e = 0; e < 4; ++e) {
          cacc[0][m2][e] += mb0[(m2 * 4 + e) * 128 + qg * 64 + l];
          cacc[1][m2][e] += mb1[(m2 * 4 + e) * 128 + qg * 64 + l];
        }
    }
  };

  stage(ktfor(0), 0);
  __syncthreads();

  for (int ss = 0; ss < nsteps; ++ss) {
    const int cur = ss & 1;
    if (ss + 1 < nsteps) stage(ktfor(ss + 1), cur ^ 1);

    const int kt = ktfor(ss);
    const unsigned short* Kb = &Kl[cur][0];
    const unsigned short* Vb = &Vl[cur][0];

    s16x8 kf[4];
    #pragma unroll
    for (int j = 0; j < 4; ++j)
      kf[j] = *(const s16x8*)&Kb[(((kh * 4 + j) * 4 + grp) * 16 + lr) * 8];

    __builtin_amdgcn_s_setprio(1);
    f32x4 sc[2][2];
    #pragma unroll
    for (int q2 = 0; q2 < 2; ++q2) {
      #pragma unroll
      for (int tt = 0; tt < 2; ++tt) {
        f32x4 a = __builtin_amdgcn_mfma_f32_16x16x32_bf16(kf[tt * 2 + 0], qf[q2][0], minit, 0, 0, 0);
        a = __builtin_amdgcn_mfma_f32_16x16x32_bf16(kf[tt * 2 + 1], qf[q2][1], a, 0, 0, 0);
        sc[q2][tt] = a;
      }
    }
    __builtin_amdgcn_s_setprio(0);

    if (kt == sup) {
      #pragma unroll
      for (int q2 = 0; q2 < 2; ++q2) {
        const int qloc = qg * 32 + q2 * 16 + lr;
        #pragma unroll
        for (int tt = 0; tt < 2; ++tt)
          #pragma unroll
          for (int e = 0; e < 4; ++e)
            if (((kh * 2 + tt) * 16 + grp * 4 + e) > qloc) sc[q2][tt][e] += -1.0e9f;
      }
    }

    #pragma unroll
    for (int q2 = 0; q2 < 2; ++q2)
      #pragma unroll
      for (int tt = 0; tt < 2; ++tt)
        #pragma unroll
        for (int e = 0; e < 4; ++e)
          sc[q2][tt][e] = fexp2(sc[q2][tt][e]);

    s16x8 pf[2];
    #pragma unroll
    for (int q2 = 0; q2 < 2; ++q2) {
      union { u32 wd[4]; s16x8 v; } pu;
      pu.wd[0] = cvtpk(sc[q2][0][0], sc[q2][0][1]);
      pu.wd[1] = cvtpk(sc[q2][0][2], sc[q2][0][3]);
      pu.wd[2] = cvtpk(sc[q2][1][0], sc[q2][1][1]);
      pu.wd[3] = cvtpk(sc[q2][1][2], sc[q2][1][3]);
      pf[q2] = pu.v;
    }

    __builtin_amdgcn_s_setprio(1);
    #pragma unroll
    for (int m2 = 0; m2 < 4; ++m2) {
      s16x8 vfr = *(const s16x8*)&Vb[((m2 * 2 + kh) * 64 + l) * 8];
      cacc[0][m2] = __builtin_amdgcn_mfma_f32_16x16x32_bf16(vfr, pf[0], cacc[0][m2], 0, 0, 0);
      cacc[1][m2] = __builtin_amdgcn_mfma_f32_16x16x32_bf16(vfr, pf[1], cacc[1][m2], 0, 0, 0);
    }
    lacc[0] = __builtin_amdgcn_mfma_f32_16x16x32_bf16(ones, pf[0], lacc[0], 0, 0, 0);
    lacc[1] = __builtin_amdgcn_mfma_f32_16x16x32_bf16(ones, pf[1], lacc[1], 0, 0, 0);
    __builtin_amdgcn_s_setprio(0);

    // role0 phase switch: merge kh partials, write FINAL light rows to ns0
    if (role == 0 && ss == pr) {
      __syncthreads();                  // all waves done reading Kl/Vl[cur]
      merge_kh(cur);
      if (kh == 0) {
        #pragma unroll
        for (int q2 = 0; q2 < 2; ++q2) {
          const int rowg = sup * 64 + qg * 32 + q2 * 16 + lr;
          unsigned short* np_ = ns0 + ((size_t)((b << 12) + rowg)) * 256 + h * 64;
          #pragma unroll
          for (int m2 = 0; m2 < 4; ++m2) {
            uint2 pk2; pk2.x = cvtpk(cacc[q2][m2][0], cacc[q2][m2][1]);
            pk2.y = cvtpk(cacc[q2][m2][2], cacc[q2][m2][3]);
            *(uint2*)&np_[m2 * 16 + grp * 4] = pk2;
          }
          if (grp == 0) lb0[(bh << 12) + rowg] = lacc[q2][0] + lred[qg][q2][lr];
        }
      }
      #pragma unroll
      for (int q2 = 0; q2 < 2; ++q2) {
        cacc[q2][0] = cacc[q2][1] = cacc[q2][2] = cacc[q2][3] = (f32x4){0.f, 0.f, 0.f, 0.f};
        lacc[q2] = (f32x4){0.f, 0.f, 0.f, 0.f};
      }
      sup = 63 - pr;
      #pragma unroll
      for (int q2 = 0; q2 < 2; ++q2) {
        const unsigned short* qp = qpb + (size_t)(sup * 64 + qg * 32 + q2 * 16 + lr) * KK;
        qf[q2][0] = *(const s16x8*)(qp + grp * 8);
        qf[q2][1] = *(const s16x8*)(qp + 32 + grp * 8);
      }
    }
    __syncthreads();
  }

  // final epilogue: merge kh, then role0 -> ns0 (heavy partial), role1 -> ns2
  merge_kh((nsteps - 1) & 1);
  if (kh == 0) {
    if (role == 0) {
      #pragma unroll
      for (int q2 = 0; q2 < 2; ++q2) {
        const int rowg = sup * 64 + qg * 32 + q2 * 16 + lr;
        unsigned short* np_ = ns0 + ((size_t)((b << 12) + rowg)) * 256 + h * 64;
        #pragma unroll
        for (int m2 = 0; m2 < 4; ++m2) {
          uint2 pk2; pk2.x = cvtpk(cacc[q2][m2][0], cacc[q2][m2][1]);
          pk2.y = cvtpk(cacc[q2][m2][2], cacc[q2][m2][3]);
          *(uint2*)&np_[m2 * 16 + grp * 4] = pk2;
        }
        if (grp == 0) lb0[(bh << 12) + rowg] = lacc[q2][0] + lred[qg][q2][lr];
      }
    } else {
      #pragma unroll
      for (int q2 = 0; q2 < 2; ++q2) {
        const int rowg = sup * 64 + qg * 32 + q2 * 16 + lr;   // >= 2048
        unsigned short* np_ = ns2 + ((size_t)((b << 11) + (rowg - 2048))) * 256 + h * 64;
        #pragma unroll
        for (int m2 = 0; m2 < 4; ++m2) {
          uint2 pk2; pk2.x = cvtpk(cacc[q2][m2][0], cacc[q2][m2][1]);
          pk2.y = cvtpk(cacc[q2][m2][2], cacc[q2][m2][3]);
          *(uint2*)&np_[m2 * 16 + grp * 4] = pk2;
        }
        if (grp == 0) lb2[(bh << 11) + (rowg - 2048)] = lacc[q2][0] + lred[qg][q2][lr];
      }
    }
  }
}

// ---------------- Kernel 3: output projection + residual + LayerNorm (MFMA) ----------------
__global__ __launch_bounds__(256, 4) void oproj_ln(
    const unsigned short* __restrict__ ns0, const unsigned short* __restrict__ ns2,
    const float* __restrict__ lb0, const float* __restrict__ lb2,
    const unsigned short* __restrict__ Wot,
    const float* __restrict__ bo, const float* __restrict__ query,
    const float* __restrict__ gamma, const float* __restrict__ beta,
    float* __restrict__ out)
{
  __shared__ __align__(16) float redS[32][4];
  __shared__ __align__(16) float redQ[32][4];

  const int t = threadIdx.x;
  const int w = t >> 6, l = t & 63, lr = l & 15, grp = l >> 4;
  const long r0 = (long)blockIdx.x * 32;
  const int n0c = w * 64;
  const int b = (int)(r0 >> 12);
  const bool heavy = ((r0 >> 11) & 1) != 0;

  float invl[2][4];
  #pragma unroll
  for (int mt = 0; mt < 2; ++mt) {
    const int grow = (int)r0 + mt * 16 + lr;
    #pragma unroll
    for (int h = 0; h < 4; ++h) {
      float lv = lb0[((b * 4 + h) << 12) + (grow & 4095)];
      if (heavy) lv += lb2[((b * 4 + h) << 11) + (grow & 2047)];
      invl[mt][h] = 1.0f / lv;
    }
  }

  f32x4 acc[2][4] = {};

  #pragma unroll
  for (int k0 = 0; k0 < 256; k0 += 32) {
    s16x8 bfr[2];
    #pragma unroll
    for (int mt = 0; mt < 2; ++mt) {
      const int grow = (int)r0 + mt * 16 + lr;
      const int c = k0 + grp * 8;
      f32x4 a0 = {0.f, 0.f, 0.f, 0.f}, a1 = {0.f, 0.f, 0.f, 0.f};
      acc8(ns0 + (size_t)grow * 256 + c, a0, a1);
      if (heavy)
        acc8(ns2 + ((size_t)((b << 11) + (grow & 2047))) * 256 + c, a0, a1);
      const float iv = invl[mt][k0 >> 6];
      a0 *= iv; a1 *= iv;
      union { u32 wd[4]; s16x8 v; } bb;
      bb.wd[0] = cvtpk(a0[0], a0[1]);
      bb.wd[1] = cvtpk(a0[2], a0[3]);
      bb.wd[2] = cvtpk(a1[0], a1[1]);
      bb.wd[3] = cvtpk(a1[2], a1[3]);
      bfr[mt] = bb.v;
    }
    #pragma unroll
    for (int nt = 0; nt < 4; ++nt) {
      s16x8 af = *(const s16x8*)(Wot + (size_t)(n0c + nt * 16 + lr) * 256 + k0 + grp * 8);
      acc[0][nt] = __builtin_amdgcn_mfma_f32_16x16x32_bf16(af, bfr[0], acc[0][nt], 0, 0, 0);
      acc[1][nt] = __builtin_amdgcn_mfma_f32_16x16x32_bf16(af, bfr[1], acc[1][nt], 0, 0, 0);
    }
  }

  float sm[2] = {0.f, 0.f}, sq[2] = {0.f, 0.f};
  #pragma unroll
  for (int mt = 0; mt < 2; ++mt) {
    const long s = r0 + mt * 16 + lr;
    #pragma unroll
    for (int nt = 0; nt < 4; ++nt) {
      const int n = n0c + nt * 16 + grp * 4;
      f32x4 v = acc[mt][nt] + *(const f32x4*)&bo[n] + *(const f32x4*)&query[s * 256 + n];
      acc[mt][nt] = v;
      sm[mt] += v[0] + v[1] + v[2] + v[3];
      sq[mt] += v[0]*v[0] + v[1]*v[1] + v[2]*v[2] + v[3]*v[3];
    }
    sm[mt] += __shfl_xor(sm[mt], 16); sm[mt] += __shfl_xor(sm[mt], 32);
    sq[mt] += __shfl_xor(sq[mt], 16); sq[mt] += __shfl_xor(sq[mt], 32);
  }
  if (grp == 0) {
    redS[0 * 16 + lr][w] = sm[0]; redQ[0 * 16 + lr][w] = sq[0];
    redS[1 * 16 + lr][w] = sm[1]; redQ[1 * 16 + lr][w] = sq[1];
  }
  __syncthreads();

  #pragma unroll
  for (int mt = 0; mt < 2; ++mt) {
    f32x4 s4 = *(const f32x4*)&redS[mt * 16 + lr][0];
    f32x4 q4 = *(const f32x4*)&redQ[mt * 16 + lr][0];
    const float tot = s4[0] + s4[1] + s4[2] + s4[3];
    const float tq  = q4[0] + q4[1] + q4[2] + q4[3];
    const float mu  = tot * 0.00390625f;
    const float var = tq * 0.00390625f - mu * mu;
    const float rs  = rsqrtf(var + 1.0e-3f);
    const long s = r0 + mt * 16 + lr;
    #pragma unroll
    for (int nt = 0; nt < 4; ++nt) {
      const int n = n0c + nt * 16 + grp * 4;
      f32x4 g = *(const f32x4*)&gamma[n];
      f32x4 bt = *(const f32x4*)&beta[n];
      f32x4 o = (acc[mt][nt] - mu) * rs * g + bt;
      *(f32x4*)&out[s * 256 + n] = o;
    }
  }
}

extern "C" void kernel_launch(void* const* d_in, const int* in_sizes, int n_in,
                              void* d_out, int out_size, void* d_ws, size_t ws_size,
                              hipStream_t stream) {
  const float* query = (const float*)d_in[0];
  const float* value = (const float*)d_in[1];
  const float* Wq    = (const float*)d_in[2];
  const float* bq    = (const float*)d_in[3];
  const float* Wk    = (const float*)d_in[4];
  const float* bk    = (const float*)d_in[5];
  const float* Wv    = (const float*)d_in[6];
  const float* bv    = (const float*)d_in[7];
  const float* Wo    = (const float*)d_in[8];
  const float* bo    = (const float*)d_in[9];
  const float* gamma = (const float*)d_in[10];
  const float* beta  = (const float*)d_in[11];
  float* out = (float*)d_out;

  char* ws = (char*)d_ws;
  unsigned short* qb  = (unsigned short*)ws;                          //  8 MiB bf16 [bh][s][dk]
  unsigned short* kbs = (unsigned short*)(ws + ((size_t)8  << 20));   //  8 MiB bf16 chunked K
  unsigned short* vts = (unsigned short*)(ws + ((size_t)16 << 20));   //  8 MiB bf16 chunked V^T
  unsigned short* ns0 = (unsigned short*)(ws + ((size_t)24 << 20));   //  8 MiB bf16 [b*4096][256]
  unsigned short* ns2 = (unsigned short*)(ws + ((size_t)32 << 20));   //  4 MiB bf16 [b*2048][256]
  float* lb0 = (float*)(ws + ((size_t)36 << 20));                     // 256 KiB f32 [16][4096]
  float* lb2 = (float*)(ws + ((size_t)36 << 20) + ((size_t)256 << 10)); // 128 KiB f32 [16][2048]
  unsigned short* Wt  = (unsigned short*)(ws + ((size_t)36 << 20) + ((size_t)512 << 10)); // 384 KiB
  unsigned short* Wot = Wt + (size_t)768 * 256;                       // 128 KiB

  wprep<<<256, 256, 0, stream>>>(Wq, Wk, Wv, Wo, Wt, Wot);
  qkv_mfma<<<768, 256, 0, stream>>>(query, value, Wt, bq, bk, bv, qb, kbs, vts);
  attn<<<1024, 256, 0, stream>>>(qb, kbs, vts, ns0, ns2, lb0, lb2);
  oproj_ln<<<512, 256, 0, stream>>>(ns0, ns2, lb0, lb2, Wot, bo, query, gamma, beta, out);
}